// Round 1
// baseline (338.879 us; speedup 1.0000x reference)
//
#include <hip/hip_runtime.h>
#include <math.h>

constexpr int B_  = 2048;
constexpr int S_  = 16;
constexpr int D_  = 512;
constexpr int CH_ = 1024;
constexpr int TB  = 8;   // samples per expert tile

// ---------------- workspace layout ----------------
// [0, B*S)                 float logits
// [LOG_BYTES, +64)         int   count[16]
// [LIST_OFF, +B*S*4)       int   list[16][B]
constexpr size_t LOG_BYTES = (size_t)B_ * S_ * sizeof(float);
constexpr size_t CNT_OFF   = LOG_BYTES;
constexpr size_t LIST_OFF  = CNT_OFF + 64;

// ---------------- kernel 1: router logits ----------------
__global__ __launch_bounds__(256) void k_router(
    const float* __restrict__ ldt, const float* __restrict__ ldr,
    const float* __restrict__ w,   const float* __restrict__ bsc,
    float* __restrict__ logits)
{
    const int wave = threadIdx.x >> 6;
    const int lane = threadIdx.x & 63;
    const int pair = blockIdx.x * 4 + wave;
    if (pair >= B_ * S_) return;
    const int b = pair >> 4;
    const int s = pair & 15;

    const float4* pt = (const float4*)(ldt + ((size_t)b * S_ + s) * D_);
    const float4* pr = (const float4*)(ldr + ((size_t)b * S_ + s) * D_);
    const float4* wt = (const float4*)(w);
    const float4* wr = (const float4*)(w + D_);

    float acc = 0.f;
    #pragma unroll
    for (int i = lane; i < D_ / 4; i += 64) {
        float4 a  = pt[i]; float4 ww = wt[i];
        acc += a.x * ww.x + a.y * ww.y + a.z * ww.z + a.w * ww.w;
        float4 c  = pr[i]; float4 w2 = wr[i];
        acc += c.x * w2.x + c.y * w2.y + c.z * w2.z + c.w * w2.w;
    }
    #pragma unroll
    for (int off = 32; off > 0; off >>= 1) acc += __shfl_down(acc, off, 64);
    if (lane == 0) logits[pair] = acc + bsc[0];
}

// ---------------- kernel 2: log_softmax + argmax + compaction ----------------
__global__ __launch_bounds__(256) void k_softmax(
    const float* __restrict__ logits,
    float* __restrict__ sld,            // [B,16] log_softmax output
    int* __restrict__ count,            // [16]
    int* __restrict__ list)             // [16][B]
{
    const int b = blockIdx.x * blockDim.x + threadIdx.x;
    if (b >= B_) return;
    float v[S_];
    float mx = -INFINITY;
    int   mi = 0;
    #pragma unroll
    for (int s = 0; s < S_; s++) {
        v[s] = logits[b * S_ + s];
        if (v[s] > mx) { mx = v[s]; mi = s; }   // strict > keeps first max
    }
    float sum = 0.f;
    #pragma unroll
    for (int s = 0; s < S_; s++) sum += expf(v[s] - mx);
    const float lse = mx + logf(sum);
    #pragma unroll
    for (int s = 0; s < S_; s++) sld[b * S_ + s] = v[s] - lse;

    const int pos = atomicAdd(&count[mi], 1);
    list[mi * B_ + pos] = b;
}

// ---------------- kernel 3: expert heads (both t and r) ----------------
__global__ __launch_bounds__(256) void k_experts(
    const float* __restrict__ ldt, const float* __restrict__ ldr,
    const float* __restrict__ Wht, const float* __restrict__ bht,
    const float* __restrict__ Wot, const float* __restrict__ bot,
    const float* __restrict__ Whr, const float* __restrict__ bhr,
    const float* __restrict__ Wor, const float* __restrict__ bor,
    const int* __restrict__ count, const int* __restrict__ list,
    float* __restrict__ pose)
{
    const int m    = blockIdx.x & (S_ - 1);
    const int tile = blockIdx.x >> 4;
    const int n    = count[m];
    const int start = tile * TB;
    if (start >= n) return;
    const int nv = min(TB, n - start);

    __shared__ float xt[TB][D_];
    __shared__ float xr[TB][D_];
    __shared__ int   bidx[TB];
    __shared__ float ored[TB][8];

    const int tid = threadIdx.x;
    if (tid < TB) bidx[tid] = (tid < nv) ? list[m * B_ + start + tid] : -1;
    if (tid >= 64 && tid < 64 + TB * 8) {
        int t2 = tid - 64;
        ored[t2 >> 3][t2 & 7] = 0.f;
    }
    __syncthreads();

    // stage x tiles (zero-pad invalid rows)
    for (int i = tid; i < TB * (D_ / 4); i += 256) {
        const int r = i >> 7;          // / 128
        const int c = i & 127;
        const int bb = bidx[r];
        float4 vt = make_float4(0.f, 0.f, 0.f, 0.f);
        float4 vr = make_float4(0.f, 0.f, 0.f, 0.f);
        if (bb >= 0) {
            vt = ((const float4*)(ldt + ((size_t)bb * S_ + m) * D_))[c];
            vr = ((const float4*)(ldr + ((size_t)bb * S_ + m) * D_))[c];
        }
        *((float4*)&xt[r][c * 4]) = vt;
        *((float4*)&xr[r][c * 4]) = vr;
    }
    __syncthreads();

    float ot[TB][3];
    float orr[TB][4];
    #pragma unroll
    for (int s = 0; s < TB; s++) {
        ot[s][0] = ot[s][1] = ot[s][2] = 0.f;
        orr[s][0] = orr[s][1] = orr[s][2] = orr[s][3] = 0.f;
    }

    const size_t wbase = (size_t)m * D_ * CH_;
    for (int cb = 0; cb < CH_; cb += 256) {
        const int ch = cb + tid;
        float at[TB], ar[TB];
        #pragma unroll
        for (int s = 0; s < TB; s++) { at[s] = 0.f; ar[s] = 0.f; }

        const float* wt = Wht + wbase + ch;
        const float* wr = Whr + wbase + ch;
        for (int d4 = 0; d4 < D_ / 4; d4++) {
            const float w0t = wt[(size_t)(d4 * 4 + 0) * CH_];
            const float w1t = wt[(size_t)(d4 * 4 + 1) * CH_];
            const float w2t = wt[(size_t)(d4 * 4 + 2) * CH_];
            const float w3t = wt[(size_t)(d4 * 4 + 3) * CH_];
            const float w0r = wr[(size_t)(d4 * 4 + 0) * CH_];
            const float w1r = wr[(size_t)(d4 * 4 + 1) * CH_];
            const float w2r = wr[(size_t)(d4 * 4 + 2) * CH_];
            const float w3r = wr[(size_t)(d4 * 4 + 3) * CH_];
            #pragma unroll
            for (int s = 0; s < TB; s++) {
                const float4 xv  = *((const float4*)&xt[s][d4 * 4]);
                at[s] += w0t * xv.x + w1t * xv.y + w2t * xv.z + w3t * xv.w;
                const float4 xv2 = *((const float4*)&xr[s][d4 * 4]);
                ar[s] += w0r * xv2.x + w1r * xv2.y + w2r * xv2.z + w3r * xv2.w;
            }
        }

        const float b1 = bht[m * CH_ + ch];
        const float b2 = bhr[m * CH_ + ch];
        const float* wo1 = Wot + ((size_t)m * CH_ + ch) * 3;
        const float* wo2 = Wor + ((size_t)m * CH_ + ch) * 4;
        const float p0 = wo1[0], p1 = wo1[1], p2 = wo1[2];
        const float q0 = wo2[0], q1 = wo2[1], q2 = wo2[2], q3 = wo2[3];
        #pragma unroll
        for (int s = 0; s < TB; s++) {
            const float h1v = at[s] + b1;
            const float h1  = 0.5f * h1v * (1.f + erff(h1v * 0.70710678118654752f));
            const float h2v = ar[s] + b2;
            const float h2  = 0.5f * h2v * (1.f + erff(h2v * 0.70710678118654752f));
            ot[s][0]  += h1 * p0; ot[s][1]  += h1 * p1; ot[s][2]  += h1 * p2;
            orr[s][0] += h2 * q0; orr[s][1] += h2 * q1; orr[s][2] += h2 * q2; orr[s][3] += h2 * q3;
        }
    }

    // reduce across threads: wave shuffle first, then one LDS atomic per wave
    #pragma unroll
    for (int s = 0; s < TB; s++) {
        #pragma unroll
        for (int j = 0; j < 3; j++) {
            float v = ot[s][j];
            #pragma unroll
            for (int off = 32; off > 0; off >>= 1) v += __shfl_down(v, off, 64);
            if ((tid & 63) == 0) atomicAdd(&ored[s][j], v);
        }
        #pragma unroll
        for (int j = 0; j < 4; j++) {
            float v = orr[s][j];
            #pragma unroll
            for (int off = 32; off > 0; off >>= 1) v += __shfl_down(v, off, 64);
            if ((tid & 63) == 0) atomicAdd(&ored[s][3 + j], v);
        }
    }
    __syncthreads();

    if (tid < nv * 7) {
        const int s = tid / 7;
        const int j = tid % 7;
        const int bb = bidx[s];
        const float bias = (j < 3) ? bot[m * 3 + j] : bor[m * 4 + (j - 3)];
        pose[(size_t)bb * 7 + j] = ored[s][j] + bias;
    }
}

// ---------------- launch ----------------
extern "C" void kernel_launch(void* const* d_in, const int* in_sizes, int n_in,
                              void* d_out, int out_size, void* d_ws, size_t ws_size,
                              hipStream_t stream)
{
    const float* ldt = (const float*)d_in[0];
    const float* ldr = (const float*)d_in[1];
    const float* wsc = (const float*)d_in[2];
    const float* bsc = (const float*)d_in[3];
    const float* Wht = (const float*)d_in[4];
    const float* bht = (const float*)d_in[5];
    const float* Wot = (const float*)d_in[6];
    const float* bot = (const float*)d_in[7];
    const float* Whr = (const float*)d_in[8];
    const float* bhr = (const float*)d_in[9];
    const float* Wor = (const float*)d_in[10];
    const float* bor = (const float*)d_in[11];

    float* pose = (float*)d_out;               // [B,7]
    float* sld  = (float*)d_out + (size_t)B_ * 7;  // [B,16]

    float* logits = (float*)d_ws;
    int*   count  = (int*)((char*)d_ws + CNT_OFF);
    int*   list   = (int*)((char*)d_ws + LIST_OFF);

    // zero expert counters (graph-capturable)
    hipMemsetAsync(count, 0, 16 * sizeof(int), stream);

    // 1) router logits
    k_router<<<dim3((B_ * S_ + 3) / 4), dim3(256), 0, stream>>>(ldt, ldr, wsc, bsc, logits);

    // 2) log_softmax + argmax + per-expert compaction
    k_softmax<<<dim3((B_ + 255) / 256), dim3(256), 0, stream>>>(logits, sld, count, list);

    // 3) expert heads (grid covers worst-case skew: 16 experts x 256 tiles)
    k_experts<<<dim3(S_ * (B_ / TB)), dim3(256), 0, stream>>>(
        ldt, ldr, Wht, bht, Wot, bot, Whr, bhr, Wor, bor, count, list, pose);
}

// Round 2
// 83.107 us; speedup vs baseline: 4.0776x; 4.0776x over previous
//
#include <hip/hip_runtime.h>
#include <hip/hip_bf16.h>
#include <math.h>

constexpr int B_  = 2048;
constexpr int S_  = 16;
constexpr int D_  = 512;
constexpr int CH_ = 1024;

// GEMM tiling for the expert hidden layer
constexpr int BM = 64;    // samples per tile
constexpr int BN = 128;   // ch columns per tile
constexpr int BK = 64;    // k step

typedef __attribute__((ext_vector_type(8))) short bf16x8;
typedef __attribute__((ext_vector_type(4))) float f32x4;

// ---------------- workspace layout ----------------
// [0, 64)        int count[16]
// [256, +128K)   int list[16][2048]
constexpr size_t CNT_OFF  = 0;
constexpr size_t LIST_OFF = 256;

static __device__ __forceinline__ short f2bf(float x) {
    __hip_bfloat16 h = __float2bfloat16(x);
    return *(short*)&h;
}

static __device__ __forceinline__ float gelu_exact(float x) {
    return 0.5f * x * (1.f + erff(x * 0.70710678118654752f));
}

// ---------------- kernel 1: router + log_softmax + argmax + compaction ----------------
// one sample per block; 16 waves, one scene per wave
__global__ __launch_bounds__(1024) void k_router_sm(
    const float* __restrict__ ldt, const float* __restrict__ ldr,
    const float* __restrict__ w,   const float* __restrict__ bsc,
    float* __restrict__ sld,       // [B,16] log_softmax out
    int* __restrict__ count, int* __restrict__ list)
{
    const int b    = blockIdx.x;
    const int wave = threadIdx.x >> 6;
    const int lane = threadIdx.x & 63;

    __shared__ float lgs[S_];

    const float4* pt = (const float4*)(ldt + ((size_t)b * S_ + wave) * D_);
    const float4* pr = (const float4*)(ldr + ((size_t)b * S_ + wave) * D_);
    const float4* wt = (const float4*)(w);
    const float4* wr = (const float4*)(w + D_);

    float acc = 0.f;
    #pragma unroll
    for (int it = 0; it < 2; it++) {
        const int i = lane + it * 64;
        float4 a  = pt[i]; float4 ww = wt[i];
        acc += a.x * ww.x + a.y * ww.y + a.z * ww.z + a.w * ww.w;
        float4 c  = pr[i]; float4 w2 = wr[i];
        acc += c.x * w2.x + c.y * w2.y + c.z * w2.z + c.w * w2.w;
    }
    #pragma unroll
    for (int off = 32; off > 0; off >>= 1) acc += __shfl_down(acc, off, 64);
    if (lane == 0) lgs[wave] = acc;
    __syncthreads();

    if (threadIdx.x < S_) {
        const int s = threadIdx.x;
        const float v = lgs[s] + bsc[0];
        // argmax with first-max tie-break (max value, min index)
        float mv = v; int mi = s;
        #pragma unroll
        for (int d = 1; d < 16; d <<= 1) {
            float ov = __shfl_xor(mv, d, 16);
            int   oi = __shfl_xor(mi, d, 16);
            if (ov > mv || (ov == mv && oi < mi)) { mv = ov; mi = oi; }
        }
        float e = expf(v - mv);
        float sum = e;
        #pragma unroll
        for (int d = 1; d < 16; d <<= 1) sum += __shfl_xor(sum, d, 16);
        const float lse = mv + logf(sum);
        sld[b * S_ + s] = v - lse;
        if (s == 0) {
            const int pos = atomicAdd(&count[mi], 1);
            list[mi * B_ + pos] = b;
        }
    }
}

// ---------------- kernel 2: expert heads, MFMA grouped GEMM + fused output layer ----------------
// grid bits: m(4) | head(1) | ct(3) | st(5)
__global__ __launch_bounds__(256) void k_expert_mfma(
    const float* __restrict__ ldt, const float* __restrict__ ldr,
    const float* __restrict__ Wht, const float* __restrict__ bht,
    const float* __restrict__ Wot, const float* __restrict__ bot,
    const float* __restrict__ Whr, const float* __restrict__ bhr,
    const float* __restrict__ Wor, const float* __restrict__ bor,
    const int* __restrict__ count, const int* __restrict__ list,
    float* __restrict__ pose)
{
    const int bid  = blockIdx.x;
    const int m    = bid & 15;
    const int head = (bid >> 4) & 1;
    const int ct   = (bid >> 5) & 7;
    const int st   = bid >> 8;

    const int n = count[m];
    if (st * BM >= n) return;

    const float* __restrict__ xsrc = head ? ldr : ldt;
    const float* __restrict__ Wh   = head ? Whr : Wht;
    const float* __restrict__ bh   = head ? bhr : bht;
    const float* __restrict__ Wo   = head ? Wor : Wot;
    const float* __restrict__ bo   = head ? bor : bot;
    const int noj    = head ? 4 : 3;
    const int jobase = head ? 3 : 0;

    const int ch0 = ct * BN;

    // LDS: XOR-swizzled bf16 tiles. element (r,k): r*64 + ((k>>3)^(r&7))*8 + (k&7)
    __shared__ short As[BM * BK];   //  8 KB : x tile  [sample][k]
    __shared__ short Bs[BN * BK];   // 16 KB : W^T tile [ch][k]
    __shared__ int   bidx[BM];

    const int tid  = threadIdx.x;
    const int wave = tid >> 6;
    const int lane = tid & 63;
    const int wr   = wave >> 1;   // row half (0/1)
    const int wc   = wave & 1;    // col half (0/1)
    const int rbase = wr * 32;
    const int cbase = wc * 64;

    if (tid < BM) {
        const int gi = st * BM + tid;
        bidx[tid] = (gi < n) ? list[m * B_ + gi] : -1;
    }
    __syncthreads();

    f32x4 acc[2][4] = {};

    for (int k0 = 0; k0 < D_; k0 += BK) {
        // ---- stage A (x rows, gathered, f32 -> bf16) ----
        {
            const int r  = tid >> 2;
            const int kc = (tid & 3) * 16;
            const int bb = bidx[r];
            float4 v0, v1, v2, v3;
            if (bb >= 0) {
                const float4* src = (const float4*)(xsrc + ((size_t)bb * S_ + m) * D_ + k0 + kc);
                v0 = src[0]; v1 = src[1]; v2 = src[2]; v3 = src[3];
            } else {
                v0 = v1 = v2 = v3 = make_float4(0.f, 0.f, 0.f, 0.f);
            }
            short tmp[16];
            tmp[0]=f2bf(v0.x); tmp[1]=f2bf(v0.y); tmp[2]=f2bf(v0.z); tmp[3]=f2bf(v0.w);
            tmp[4]=f2bf(v1.x); tmp[5]=f2bf(v1.y); tmp[6]=f2bf(v1.z); tmp[7]=f2bf(v1.w);
            tmp[8]=f2bf(v2.x); tmp[9]=f2bf(v2.y); tmp[10]=f2bf(v2.z); tmp[11]=f2bf(v2.w);
            tmp[12]=f2bf(v3.x); tmp[13]=f2bf(v3.y); tmp[14]=f2bf(v3.z); tmp[15]=f2bf(v3.w);
            const int u0 = kc >> 3;
            *(bf16x8*)&As[r * 64 + ((u0     ^ (r & 7)) << 3)] = *(bf16x8*)&tmp[0];
            *(bf16x8*)&As[r * 64 + (((u0+1) ^ (r & 7)) << 3)] = *(bf16x8*)&tmp[8];
        }
        // ---- stage B (W slice, transpose to [ch][k], f32 -> bf16) ----
        {
            const int k  = tid >> 2;
            const size_t rowbase = (size_t)m * D_ * CH_ + (size_t)(k0 + k) * CH_ + ch0;
            #pragma unroll
            for (int i = 0; i < 8; i++) {
                const int chl = (tid & 3) * 4 + i * 16;
                const float4 wv = *(const float4*)(Wh + rowbase + chl);
                #pragma unroll
                for (int c = 0; c < 4; c++) {
                    const int ch = chl + c;
                    const float f = (c == 0) ? wv.x : (c == 1) ? wv.y : (c == 2) ? wv.z : wv.w;
                    Bs[ch * 64 + (((k >> 3) ^ (ch & 7)) << 3) + (k & 7)] = f2bf(f);
                }
            }
        }
        __syncthreads();

        // ---- MFMA ----
        #pragma unroll
        for (int kk = 0; kk < BK; kk += 32) {
            const int ub = (kk >> 3) + (lane >> 4);
            bf16x8 a[2], bfr[4];
            #pragma unroll
            for (int fm = 0; fm < 2; fm++) {
                const int r = rbase + fm * 16 + (lane & 15);
                a[fm] = *(bf16x8*)&As[r * 64 + ((ub ^ (r & 7)) << 3)];
            }
            #pragma unroll
            for (int fn = 0; fn < 4; fn++) {
                const int c = cbase + fn * 16 + (lane & 15);
                bfr[fn] = *(bf16x8*)&Bs[c * 64 + ((ub ^ (c & 7)) << 3)];
            }
            #pragma unroll
            for (int fm = 0; fm < 2; fm++)
                #pragma unroll
                for (int fn = 0; fn < 4; fn++)
                    acc[fm][fn] = __builtin_amdgcn_mfma_f32_16x16x32_bf16(a[fm], bfr[fn], acc[fm][fn], 0, 0, 0);
        }
        __syncthreads();
    }

    // ---- epilogue: bias + GELU + Wo partial + 16-lane reduce + atomicAdd ----
    float g[2][4][4];
    float wo_l[4][4];
    #pragma unroll
    for (int fn = 0; fn < 4; fn++) {
        const int ch = ch0 + cbase + fn * 16 + (lane & 15);
        const float bias = bh[m * CH_ + ch];
        #pragma unroll
        for (int fm = 0; fm < 2; fm++)
            #pragma unroll
            for (int j = 0; j < 4; j++)
                g[fm][fn][j] = gelu_exact(acc[fm][fn][j] + bias);
        #pragma unroll
        for (int jo = 0; jo < 4; jo++)
            wo_l[fn][jo] = (jo < noj) ? Wo[(size_t)(m * CH_ + ch) * noj + jo] : 0.f;
    }

    #pragma unroll
    for (int fm = 0; fm < 2; fm++) {
        #pragma unroll
        for (int j = 0; j < 4; j++) {
            const int lr = rbase + fm * 16 + ((lane >> 4) << 2) + j;
            const int bb = bidx[lr];
            #pragma unroll
            for (int jo = 0; jo < 4; jo++) {
                if (jo >= noj) continue;
                float v = 0.f;
                #pragma unroll
                for (int fn = 0; fn < 4; fn++) v += g[fm][fn][j] * wo_l[fn][jo];
                #pragma unroll
                for (int d = 1; d < 16; d <<= 1) v += __shfl_xor(v, d, 16);
                if ((lane & 15) == 0 && bb >= 0) {
                    if (ct == 0 && wc == 0) v += bo[m * noj + jo];
                    atomicAdd(&pose[(size_t)bb * 7 + jobase + jo], v);
                }
            }
        }
    }
}

// ---------------- launch ----------------
extern "C" void kernel_launch(void* const* d_in, const int* in_sizes, int n_in,
                              void* d_out, int out_size, void* d_ws, size_t ws_size,
                              hipStream_t stream)
{
    const float* ldt = (const float*)d_in[0];
    const float* ldr = (const float*)d_in[1];
    const float* wsc = (const float*)d_in[2];
    const float* bsc = (const float*)d_in[3];
    const float* Wht = (const float*)d_in[4];
    const float* bht = (const float*)d_in[5];
    const float* Wot = (const float*)d_in[6];
    const float* bot = (const float*)d_in[7];
    const float* Whr = (const float*)d_in[8];
    const float* bhr = (const float*)d_in[9];
    const float* Wor = (const float*)d_in[10];
    const float* bor = (const float*)d_in[11];

    float* pose = (float*)d_out;                   // [B,7]
    float* sld  = (float*)d_out + (size_t)B_ * 7;  // [B,16]

    int* count = (int*)((char*)d_ws + CNT_OFF);
    int* list  = (int*)((char*)d_ws + LIST_OFF);

    hipMemsetAsync(count, 0, 16 * sizeof(int), stream);
    hipMemsetAsync(pose, 0, (size_t)B_ * 7 * sizeof(float), stream);

    // 1) router + softmax + argmax + compaction (one sample per block)
    k_router_sm<<<dim3(B_), dim3(1024), 0, stream>>>(ldt, ldr, wsc, bsc, sld, count, list);

    // 2) expert heads: grid = m(16) x head(2) x chtile(8) x sampletile(32)
    k_expert_mfma<<<dim3(16 * 2 * 8 * 32), dim3(256), 0, stream>>>(
        ldt, ldr, Wht, bht, Wot, bot, Whr, bhr, Wor, bor, count, list, pose);
}